// Round 5
// baseline (226.529 us; speedup 1.0000x reference)
//
#include <hip/hip_runtime.h>
#include <cstdint>
#include <cstddef>

typedef _Float16 half8 __attribute__((ext_vector_type(8)));
typedef _Float16 half4 __attribute__((ext_vector_type(4)));
typedef float f32x4 __attribute__((ext_vector_type(4)));

#define MFMA16(A,B,C) __builtin_amdgcn_mfma_f32_16x16x32_f16(A,B,C,0,0,0)

// ---------------- K0: bulk f32 -> f16 convert (X, Wi, Wo) ----------------
__global__ __launch_bounds__(256) void cvt_f16(
    const float* __restrict__ X, const float* __restrict__ Wi, const float* __restrict__ Wo,
    _Float16* __restrict__ Xh, _Float16* __restrict__ Wih, _Float16* __restrict__ Woh)
{
    const size_t i8 = ((size_t)blockIdx.x * 256 + threadIdx.x) * 8;
    const size_t NX = (size_t)4194304, NWI = 786432;
    const float* src; _Float16* dst; size_t off;
    if (i8 < NX) { src = X; dst = Xh; off = i8; }
    else if (i8 < NX + NWI) { src = Wi; dst = Wih; off = i8 - NX; }
    else { src = Wo; dst = Woh; off = i8 - NX - NWI; }
    f32x4 v0 = *(const f32x4*)(src + off);
    f32x4 v1 = *(const f32x4*)(src + off + 4);
    half8 r;
    r[0]=(_Float16)v0[0]; r[1]=(_Float16)v0[1]; r[2]=(_Float16)v0[2]; r[3]=(_Float16)v0[3];
    r[4]=(_Float16)v1[0]; r[5]=(_Float16)v1[1]; r[6]=(_Float16)v1[2]; r[7]=(_Float16)v1[3];
    *(half8*)(dst + off) = r;
}

// ---------------- K1: QKV projection (f16 MFMA, f16 inputs) ----------------
__global__ __launch_bounds__(256) void qkv_mfma(
    const _Float16* __restrict__ X, const _Float16* __restrict__ W,
    const float* __restrict__ bias, const float* __restrict__ gate,
    _Float16* __restrict__ Qo, _Float16* __restrict__ Ko, _Float16* __restrict__ Vt)
{
    __shared__ _Float16 As[128][72];
    __shared__ _Float16 Bs[64][72];
    const int tid = threadIdx.x;
    const int lane = tid & 63, wv = tid >> 6;
    const int l15 = lane & 15, g = lane >> 4;
    const int wr = wv >> 1, wc = wv & 1;
    const int j0 = blockIdx.x * 64, r0 = blockIdx.y * 128;
    f32x4 acc[4][2] = {};
    const int arow = tid >> 1, ahf = tid & 1;
    const int brow = tid >> 2, bc = tid & 3;
    for (int k0 = 0; k0 < 512; k0 += 64) {
        const _Float16* srca = X + (size_t)(r0 + arow) * 512 + k0 + ahf * 32;
#pragma unroll
        for (int c = 0; c < 4; ++c)
            *(half8*)&As[arow][ahf * 32 + c * 8] = *(const half8*)(srca + c * 8);
        const _Float16* srcb = W + (size_t)(j0 + brow) * 512 + k0 + bc * 16;
#pragma unroll
        for (int c = 0; c < 2; ++c)
            *(half8*)&Bs[brow][bc * 16 + c * 8] = *(const half8*)(srcb + c * 8);
        __syncthreads();
#pragma unroll
        for (int kt = 0; kt < 2; ++kt) {
            half8 bf0 = *(half8*)&Bs[32 * wc + l15][kt * 32 + g * 8];
            half8 bf1 = *(half8*)&Bs[32 * wc + 16 + l15][kt * 32 + g * 8];
#pragma unroll
            for (int ri = 0; ri < 4; ++ri) {
                half8 af = *(half8*)&As[64 * wr + 16 * ri + l15][kt * 32 + g * 8];
                acc[ri][0] = MFMA16(af, bf0, acc[ri][0]);
                acc[ri][1] = MFMA16(af, bf1, acc[ri][1]);
            }
        }
        __syncthreads();
    }
#pragma unroll
    for (int ri = 0; ri < 4; ++ri) {
#pragma unroll
        for (int cj = 0; cj < 2; ++cj) {
            const int col = j0 + 32 * wc + 16 * cj + l15;
            const int sec = col >> 9, hh = (col >> 6) & 7, d = col & 63;
            const float bv = bias[col];
#pragma unroll
            for (int r = 0; r < 4; ++r) {
                const int row = r0 + 64 * wr + 16 * ri + 4 * g + r;
                const int b = row & 3, s = row >> 2;
                const float v = acc[ri][cj][r];
                if (sec == 0)
                    Qo[((size_t)(b * 8 + hh) * 2048 + s) * 64 + d] = (_Float16)((v + bv) * 0.125f);
                else if (sec == 1)
                    Ko[((size_t)(b * 8 + hh) * 2048 + s) * 64 + d] = (_Float16)(v + bv);
                else
                    Vt[((size_t)(b * 8 + hh) * 64 + d) * 2048 + s] = (_Float16)(v * gate[b] + bv);
            }
        }
    }
}

// ---------------- K2: flash attention, KV-split 2x, 32 q-rows/wave ----------------
// Block = (b, h, 64 q-rows); wave w: qt=w&1 (32-row q-subtile), half=w>>1 (kv half).
// Each 128-thread pair stages its own half's K/V tile. Final flash-merge via LDS.
__global__ __launch_bounds__(256, 4) void attn_mfma(
    const _Float16* __restrict__ Q, const _Float16* __restrict__ K,
    const _Float16* __restrict__ V, const float* __restrict__ M,
    _Float16* __restrict__ AO)
{
    __shared__ _Float16 Kl[2][64][72];   // [half][kv][d]
    __shared__ _Float16 Vl[2][64][76];   // [half][d][kv_local]
    const int tid = threadIdx.x;
    const int lane = tid & 63, w = tid >> 6;
    const int l15 = lane & 15, g = lane >> 4;
    const int qt = w & 1, half = w >> 1;
    const int bid = blockIdx.x;
    const int h = bid & 7, b = (bid >> 3) & 3, sg = bid >> 5;
    const int s0 = sg * 64 + qt * 32;
    const size_t bh = (size_t)b * 8 + h;
    const _Float16* Qp = Q + bh * 2048 * 64;
    const _Float16* Kp = K + bh * 2048 * 64;
    const _Float16* Vp = V + bh * 64 * 2048;
    const float* Mp = M + (size_t)h * 2048 * 2048 + (size_t)half * 1024;

    // Q fragments direct from global (32 rows)
    half8 qf[2][2];
#pragma unroll
    for (int qj = 0; qj < 2; ++qj)
#pragma unroll
        for (int kt = 0; kt < 2; ++kt)
            qf[qj][kt] = *(const half8*)(Qp + (size_t)(s0 + 16 * qj + l15) * 64 + kt * 32 + g * 8);

    // staging: 128 threads per half; thread covers one row, 32 cols of K and V^T
    const int ptid = tid & 127;
    const int srow = ptid >> 1, scg = (ptid & 1) * 32;
    const int kvbase = half * 1024;
    half8 kr[4], vr[4];
#pragma unroll
    for (int c = 0; c < 4; ++c) {
        kr[c] = *(const half8*)(Kp + (size_t)(kvbase + srow) * 64 + scg + c * 8);
        vr[c] = *(const half8*)(Vp + (size_t)srow * 2048 + kvbase + scg + c * 8);
    }

    f32x4 O[4][2] = {};
    float ms[2] = {-1e30f, -1e30f}, ls[2] = {0.f, 0.f};

    for (int tl = 0; tl < 16; ++tl) {
        __syncthreads();   // all readers of Kl/Vl done
#pragma unroll
        for (int c = 0; c < 4; ++c) {
            *(half8*)&Kl[half][srow][scg + c * 8] = kr[c];
            *(half8*)&Vl[half][srow][scg + c * 8] = vr[c];
        }
        // issue prefetch for next tile (lands during compute)
        const int tn = (tl + 1) & 15;
#pragma unroll
        for (int c = 0; c < 4; ++c) {
            kr[c] = *(const half8*)(Kp + (size_t)(kvbase + tn * 64 + srow) * 64 + scg + c * 8);
            vr[c] = *(const half8*)(Vp + (size_t)srow * 2048 + kvbase + tn * 64 + scg + c * 8);
        }
        __syncthreads();   // LDS tile ready

        const int t0 = tl * 64;
        // QK^T with JIT mask load as C-init
        f32x4 St[4][2];
#pragma unroll
        for (int m = 0; m < 4; ++m) {
            const float* mrow = Mp + (size_t)(s0 + l15) * 2048 + t0 + 16 * m + 4 * g;
            f32x4 mc0 = *(const f32x4*)(mrow);
            f32x4 mc1 = *(const f32x4*)(mrow + (size_t)16 * 2048);
            half8 kf0 = *(half8*)&Kl[half][16 * m + l15][g * 8];
            half8 kf1 = *(half8*)&Kl[half][16 * m + l15][32 + g * 8];
            St[m][0] = MFMA16(kf0, qf[0][0], mc0);
            St[m][0] = MFMA16(kf1, qf[0][1], St[m][0]);
            St[m][1] = MFMA16(kf0, qf[1][0], mc1);
            St[m][1] = MFMA16(kf1, qf[1][1], St[m][1]);
        }

        // online softmax over kv, defer-max THR=8
#pragma unroll
        for (int qj = 0; qj < 2; ++qj) {
            float tm = -1e30f;
#pragma unroll
            for (int m = 0; m < 4; ++m)
#pragma unroll
                for (int r = 0; r < 4; ++r) tm = fmaxf(tm, St[m][qj][r]);
            tm = fmaxf(tm, __shfl_xor(tm, 16));
            tm = fmaxf(tm, __shfl_xor(tm, 32));
            if (!__all(tm <= ms[qj] + 8.0f)) {
                const float mn = fmaxf(ms[qj], tm);
                const float al = __expf(ms[qj] - mn);
                ls[qj] *= al;
#pragma unroll
                for (int di = 0; di < 4; ++di) {
                    O[di][qj][0] *= al; O[di][qj][1] *= al;
                    O[di][qj][2] *= al; O[di][qj][3] *= al;
                }
                ms[qj] = mn;
            }
            float ps = 0.f;
#pragma unroll
            for (int m = 0; m < 4; ++m)
#pragma unroll
                for (int r = 0; r < 4; ++r) {
                    const float p = __expf(St[m][qj][r] - ms[qj]);
                    St[m][qj][r] = p; ps += p;
                }
            ps += __shfl_xor(ps, 16);
            ps += __shfl_xor(ps, 32);
            ls[qj] += ps;
        }

        // P fragments from St regs (k-map {4g+j, 16+4g+(j-4)})
        half8 pf[2][2];
#pragma unroll
        for (int qj = 0; qj < 2; ++qj)
#pragma unroll
            for (int kt = 0; kt < 2; ++kt) {
                half8 p;
                p[0] = (_Float16)St[2 * kt][qj][0]; p[1] = (_Float16)St[2 * kt][qj][1];
                p[2] = (_Float16)St[2 * kt][qj][2]; p[3] = (_Float16)St[2 * kt][qj][3];
                p[4] = (_Float16)St[2 * kt + 1][qj][0]; p[5] = (_Float16)St[2 * kt + 1][qj][1];
                p[6] = (_Float16)St[2 * kt + 1][qj][2]; p[7] = (_Float16)St[2 * kt + 1][qj][3];
                pf[qj][kt] = p;
            }

        // O^T[d][q] += V^T · P^T (V frags use the same split k-map)
#pragma unroll
        for (int kt = 0; kt < 2; ++kt)
#pragma unroll
            for (int di = 0; di < 4; ++di) {
                half4 lo = *(half4*)&Vl[half][16 * di + l15][kt * 32 + 4 * g];
                half4 hi = *(half4*)&Vl[half][16 * di + l15][kt * 32 + 16 + 4 * g];
                half8 vf;
                vf[0] = lo[0]; vf[1] = lo[1]; vf[2] = lo[2]; vf[3] = lo[3];
                vf[4] = hi[0]; vf[5] = hi[1]; vf[6] = hi[2]; vf[7] = hi[3];
#pragma unroll
                for (int qj = 0; qj < 2; ++qj)
                    O[di][qj] = MFMA16(vf, pf[qj][kt], O[di][qj]);
            }
    }

    // ---------------- flash-merge of the two kv halves ----------------
    __syncthreads();
    float* Ml = (float*)&Kl[0][0][0];   // [qt][lane][36] = 18432 B (fits in Kl)
    if (half == 1) {
        float* dstp = Ml + ((size_t)qt * 64 + lane) * 36;
#pragma unroll
        for (int di = 0; di < 4; ++di)
#pragma unroll
            for (int qj = 0; qj < 2; ++qj)
                *(f32x4*)(dstp + di * 8 + qj * 4) = O[di][qj];
        dstp[32] = ms[0]; dstp[33] = ls[0]; dstp[34] = ms[1]; dstp[35] = ls[1];
    }
    __syncthreads();
    if (half == 0) {
        const float* srcp = Ml + ((size_t)qt * 64 + lane) * 36;
#pragma unroll
        for (int qj = 0; qj < 2; ++qj) {
            const float m1 = srcp[32 + 2 * qj], l1 = srcp[33 + 2 * qj];
            const float mm = fmaxf(ms[qj], m1);
            const float w0 = __expf(ms[qj] - mm), w1 = __expf(m1 - mm);
            const float inv = 1.0f / (ls[qj] * w0 + l1 * w1);
            const int q = s0 + 16 * qj + l15;
            _Float16* dst = AO + ((size_t)q * 4 + b) * 512 + h * 64;
#pragma unroll
            for (int di = 0; di < 4; ++di) {
                const f32x4 o1 = *(const f32x4*)(srcp + di * 8 + qj * 4);
                half4 o;
                o[0] = (_Float16)((O[di][qj][0] * w0 + o1[0] * w1) * inv);
                o[1] = (_Float16)((O[di][qj][1] * w0 + o1[1] * w1) * inv);
                o[2] = (_Float16)((O[di][qj][2] * w0 + o1[2] * w1) * inv);
                o[3] = (_Float16)((O[di][qj][3] * w0 + o1[3] * w1) * inv);
                *(half4*)(dst + 16 * di + 4 * g) = o;
            }
        }
    }
}

// ---------------- K3: output projection (f16 inputs, f32 out) ----------------
__global__ __launch_bounds__(256) void oproj_mfma(
    const _Float16* __restrict__ A, const _Float16* __restrict__ W,
    const float* __restrict__ bias, float* __restrict__ Out)
{
    __shared__ _Float16 As[128][72];
    __shared__ _Float16 Bs[64][72];
    const int tid = threadIdx.x;
    const int lane = tid & 63, wv = tid >> 6;
    const int l15 = lane & 15, g = lane >> 4;
    const int wr = wv >> 1, wc = wv & 1;
    const int j0 = blockIdx.x * 64, r0 = blockIdx.y * 128;
    f32x4 acc[4][2] = {};
    const int arow = tid >> 1, ahf = tid & 1;
    const int brow = tid >> 2, bc = tid & 3;
    for (int k0 = 0; k0 < 512; k0 += 64) {
        const _Float16* srca = A + (size_t)(r0 + arow) * 512 + k0 + ahf * 32;
#pragma unroll
        for (int c = 0; c < 4; ++c)
            *(half8*)&As[arow][ahf * 32 + c * 8] = *(const half8*)(srca + c * 8);
        const _Float16* srcb = W + (size_t)(j0 + brow) * 512 + k0 + bc * 16;
#pragma unroll
        for (int c = 0; c < 2; ++c)
            *(half8*)&Bs[brow][bc * 16 + c * 8] = *(const half8*)(srcb + c * 8);
        __syncthreads();
#pragma unroll
        for (int kt = 0; kt < 2; ++kt) {
            half8 bf0 = *(half8*)&Bs[32 * wc + l15][kt * 32 + g * 8];
            half8 bf1 = *(half8*)&Bs[32 * wc + 16 + l15][kt * 32 + g * 8];
#pragma unroll
            for (int ri = 0; ri < 4; ++ri) {
                half8 af = *(half8*)&As[64 * wr + 16 * ri + l15][kt * 32 + g * 8];
                acc[ri][0] = MFMA16(af, bf0, acc[ri][0]);
                acc[ri][1] = MFMA16(af, bf1, acc[ri][1]);
            }
        }
        __syncthreads();
    }
#pragma unroll
    for (int ri = 0; ri < 4; ++ri) {
#pragma unroll
        for (int cj = 0; cj < 2; ++cj) {
            const int col = j0 + 32 * wc + 16 * cj + l15;
            const float bv = bias[col];
#pragma unroll
            for (int r = 0; r < 4; ++r) {
                const int row = r0 + 64 * wr + 16 * ri + 4 * g + r;
                Out[(size_t)row * 512 + col] = acc[ri][cj][r] + bv;
            }
        }
    }
}

extern "C" void kernel_launch(void* const* d_in, const int* in_sizes, int n_in,
                              void* d_out, int out_size, void* d_ws, size_t ws_size,
                              hipStream_t stream)
{
    (void)in_sizes; (void)n_in; (void)out_size; (void)ws_size;
    const float* X    = (const float*)d_in[0];  // (S,B,D)
    const float* Mask = (const float*)d_in[1];  // (H,S,S)
    const float* gate = (const float*)d_in[2];  // (1,B,1)
    const float* Wi   = (const float*)d_in[3];  // (3D,D)
    const float* bi   = (const float*)d_in[4];  // (3D)
    const float* Wo   = (const float*)d_in[5];  // (D,D)
    const float* bo   = (const float*)d_in[6];  // (D)
    _Float16* ws = (_Float16*)d_ws;
    const size_t plane = (size_t)4 * 8 * 2048 * 64;  // 4,194,304
    _Float16* Qh  = ws;
    _Float16* Kh  = ws + plane;
    _Float16* Vt  = ws + 2 * plane;
    _Float16* AO  = ws + 3 * plane;
    _Float16* Xh  = ws + 4 * plane;              // 4,194,304 (== plane)
    _Float16* Wih = ws + 5 * plane;              // 786,432
    _Float16* Woh = ws + 5 * plane + 786432;     // 262,144

    cvt_f16<<<dim3(2560), 256, 0, stream>>>(X, Wi, Wo, Xh, Wih, Woh);
    qkv_mfma<<<dim3(24, 64), 256, 0, stream>>>(Xh, Wih, bi, gate, Qh, Kh, Vt);
    attn_mfma<<<dim3(1024), 256, 0, stream>>>(Qh, Kh, Vt, Mask, AO);
    oproj_mfma<<<dim3(8, 64), 256, 0, stream>>>(AO, Woh, bo, (float*)d_out);
}

// Round 6
// 145.215 us; speedup vs baseline: 1.5600x; 1.5600x over previous
//
#include <hip/hip_runtime.h>
#include <cstdint>
#include <cstddef>

typedef _Float16 half8 __attribute__((ext_vector_type(8)));
typedef _Float16 half4 __attribute__((ext_vector_type(4)));
typedef float f32x4 __attribute__((ext_vector_type(4)));

#define MFMA16(A,B,C) __builtin_amdgcn_mfma_f32_16x16x32_f16(A,B,C,0,0,0)

// ---------------- K0: bulk f32 -> f16 convert (X, Wi, Wo) ----------------
__global__ __launch_bounds__(256) void cvt_f16(
    const float* __restrict__ X, const float* __restrict__ Wi, const float* __restrict__ Wo,
    _Float16* __restrict__ Xh, _Float16* __restrict__ Wih, _Float16* __restrict__ Woh)
{
    const size_t i8 = ((size_t)blockIdx.x * 256 + threadIdx.x) * 8;
    const size_t NX = (size_t)4194304, NWI = 786432;
    const float* src; _Float16* dst; size_t off;
    if (i8 < NX) { src = X; dst = Xh; off = i8; }
    else if (i8 < NX + NWI) { src = Wi; dst = Wih; off = i8 - NX; }
    else { src = Wo; dst = Woh; off = i8 - NX - NWI; }
    f32x4 v0 = *(const f32x4*)(src + off);
    f32x4 v1 = *(const f32x4*)(src + off + 4);
    half8 r;
    r[0]=(_Float16)v0[0]; r[1]=(_Float16)v0[1]; r[2]=(_Float16)v0[2]; r[3]=(_Float16)v0[3];
    r[4]=(_Float16)v1[0]; r[5]=(_Float16)v1[1]; r[6]=(_Float16)v1[2]; r[7]=(_Float16)v1[3];
    *(half8*)(dst + off) = r;
}

// ---------------- K1: QKV projection (f16 MFMA, f16 inputs) ----------------
__global__ __launch_bounds__(256) void qkv_mfma(
    const _Float16* __restrict__ X, const _Float16* __restrict__ W,
    const float* __restrict__ bias, const float* __restrict__ gate,
    _Float16* __restrict__ Qo, _Float16* __restrict__ Ko, _Float16* __restrict__ Vt)
{
    __shared__ _Float16 As[128][72];
    __shared__ _Float16 Bs[64][72];
    const int tid = threadIdx.x;
    const int lane = tid & 63, wv = tid >> 6;
    const int l15 = lane & 15, g = lane >> 4;
    const int wr = wv >> 1, wc = wv & 1;
    const int j0 = blockIdx.x * 64, r0 = blockIdx.y * 128;
    f32x4 acc[4][2] = {};
    const int arow = tid >> 1, ahf = tid & 1;
    const int brow = tid >> 2, bc = tid & 3;
    for (int k0 = 0; k0 < 512; k0 += 64) {
        const _Float16* srca = X + (size_t)(r0 + arow) * 512 + k0 + ahf * 32;
#pragma unroll
        for (int c = 0; c < 4; ++c)
            *(half8*)&As[arow][ahf * 32 + c * 8] = *(const half8*)(srca + c * 8);
        const _Float16* srcb = W + (size_t)(j0 + brow) * 512 + k0 + bc * 16;
#pragma unroll
        for (int c = 0; c < 2; ++c)
            *(half8*)&Bs[brow][bc * 16 + c * 8] = *(const half8*)(srcb + c * 8);
        __syncthreads();
#pragma unroll
        for (int kt = 0; kt < 2; ++kt) {
            half8 bf0 = *(half8*)&Bs[32 * wc + l15][kt * 32 + g * 8];
            half8 bf1 = *(half8*)&Bs[32 * wc + 16 + l15][kt * 32 + g * 8];
#pragma unroll
            for (int ri = 0; ri < 4; ++ri) {
                half8 af = *(half8*)&As[64 * wr + 16 * ri + l15][kt * 32 + g * 8];
                acc[ri][0] = MFMA16(af, bf0, acc[ri][0]);
                acc[ri][1] = MFMA16(af, bf1, acc[ri][1]);
            }
        }
        __syncthreads();
    }
#pragma unroll
    for (int ri = 0; ri < 4; ++ri) {
#pragma unroll
        for (int cj = 0; cj < 2; ++cj) {
            const int col = j0 + 32 * wc + 16 * cj + l15;
            const int sec = col >> 9, hh = (col >> 6) & 7, d = col & 63;
            const float bv = bias[col];
#pragma unroll
            for (int r = 0; r < 4; ++r) {
                const int row = r0 + 64 * wr + 16 * ri + 4 * g + r;
                const int b = row & 3, s = row >> 2;
                const float v = acc[ri][cj][r];
                if (sec == 0)
                    Qo[((size_t)(b * 8 + hh) * 2048 + s) * 64 + d] = (_Float16)((v + bv) * 0.125f);
                else if (sec == 1)
                    Ko[((size_t)(b * 8 + hh) * 2048 + s) * 64 + d] = (_Float16)(v + bv);
                else
                    Vt[((size_t)(b * 8 + hh) * 64 + d) * 2048 + s] = (_Float16)(v * gate[b] + bv);
            }
        }
    }
}

// ---------------- K2: flash attention, 32 q-rows/wave, kv-split across blocks ----
// Block = (b, h, 128 q-rows, kv-half). Wave w handles s0 = sg*128 + w*32.
// Single barrier per tile with double-buffered Kl/Vl. Partial (O/l, m+log l)
// written to P[kvh] / Lb; merged by merge_attn.
__global__ __launch_bounds__(256) void attn_mfma(
    const _Float16* __restrict__ Q, const _Float16* __restrict__ K,
    const _Float16* __restrict__ V, const float* __restrict__ M,
    _Float16* __restrict__ P0, _Float16* __restrict__ P1, float* __restrict__ Lb)
{
    __shared__ _Float16 Kl[2][64][72];
    __shared__ _Float16 Vl[2][64][76];
    const int tid = threadIdx.x;
    const int lane = tid & 63, w = tid >> 6;
    const int l15 = lane & 15, g = lane >> 4;
    const int bid = blockIdx.x;
    const int h = bid & 7, b = (bid >> 3) & 3, sg = (bid >> 5) & 15, kvh = bid >> 9;
    const int s0 = sg * 128 + w * 32;
    const size_t bh = (size_t)b * 8 + h;
    const _Float16* Qp = Q + bh * 2048 * 64;
    const _Float16* Kp = K + bh * 2048 * 64 + (size_t)kvh * 1024 * 64;
    const _Float16* Vp = V + bh * 64 * 2048 + kvh * 1024;   // [d][s], col offset
    const float* Mp = M + (size_t)h * 2048 * 2048 + kvh * 1024;

    // Q fragments direct from global (32 rows)
    half8 qf[2][2];
#pragma unroll
    for (int qj = 0; qj < 2; ++qj)
#pragma unroll
        for (int kt = 0; kt < 2; ++kt)
            qf[qj][kt] = *(const half8*)(Qp + (size_t)(s0 + 16 * qj + l15) * 64 + kt * 32 + g * 8);

    // stage-reg prologue (tile 0 of this half): thread = one row, 16 cols
    const int srow = tid >> 2, scg = (tid & 3) * 16;
    half8 kr0 = *(const half8*)(Kp + (size_t)srow * 64 + scg);
    half8 kr1 = *(const half8*)(Kp + (size_t)srow * 64 + scg + 8);
    half8 vr0 = *(const half8*)(Vp + (size_t)srow * 2048 + scg);
    half8 vr1 = *(const half8*)(Vp + (size_t)srow * 2048 + scg + 8);

    // mask prefetch (tile 0)
    f32x4 mc[4][2];
#pragma unroll
    for (int m = 0; m < 4; ++m)
#pragma unroll
        for (int qj = 0; qj < 2; ++qj)
            mc[m][qj] = *(const f32x4*)(Mp + (size_t)(s0 + 16 * qj + l15) * 2048 + 16 * m + 4 * g);

    f32x4 O[4][2] = {};
    float ms[2] = {-1e30f, -1e30f}, ls[2] = {0.f, 0.f};

    for (int tl = 0; tl < 16; ++tl) {
        const int cur = tl & 1;
        // write staged tile into buf[cur]; prior readers of buf[cur] (tile tl-2)
        // all passed the tl-1 barrier -> safe with one barrier per tile
        *(half8*)&Kl[cur][srow][scg]     = kr0;
        *(half8*)&Kl[cur][srow][scg + 8] = kr1;
        *(half8*)&Vl[cur][srow][scg]     = vr0;
        *(half8*)&Vl[cur][srow][scg + 8] = vr1;
        // issue global loads for next tile (land during this tile's compute)
        const int tn = ((tl + 1) & 15) * 64;
        kr0 = *(const half8*)(Kp + (size_t)(tn + srow) * 64 + scg);
        kr1 = *(const half8*)(Kp + (size_t)(tn + srow) * 64 + scg + 8);
        vr0 = *(const half8*)(Vp + (size_t)srow * 2048 + tn + scg);
        vr1 = *(const half8*)(Vp + (size_t)srow * 2048 + tn + scg + 8);
        __syncthreads();

        const int t0 = tl * 64;
        // QK^T with mask as C-init
        f32x4 St[4][2];
#pragma unroll
        for (int m = 0; m < 4; ++m) {
            half8 kf0 = *(half8*)&Kl[cur][16 * m + l15][g * 8];
            half8 kf1 = *(half8*)&Kl[cur][16 * m + l15][32 + g * 8];
#pragma unroll
            for (int qj = 0; qj < 2; ++qj) {
                St[m][qj] = MFMA16(kf0, qf[qj][0], mc[m][qj]);
                St[m][qj] = MFMA16(kf1, qf[qj][1], St[m][qj]);
            }
        }
        // prefetch mask for next tile
#pragma unroll
        for (int m = 0; m < 4; ++m)
#pragma unroll
            for (int qj = 0; qj < 2; ++qj)
                mc[m][qj] = *(const f32x4*)(Mp + (size_t)(s0 + 16 * qj + l15) * 2048 + tn + 16 * m + 4 * g);

        // online softmax over kv with defer-max (THR=8)
#pragma unroll
        for (int qj = 0; qj < 2; ++qj) {
            float tm = -1e30f;
#pragma unroll
            for (int m = 0; m < 4; ++m)
#pragma unroll
                for (int r = 0; r < 4; ++r) tm = fmaxf(tm, St[m][qj][r]);
            tm = fmaxf(tm, __shfl_xor(tm, 16));
            tm = fmaxf(tm, __shfl_xor(tm, 32));
            if (!__all(tm <= ms[qj] + 8.0f)) {
                const float mn = fmaxf(ms[qj], tm);
                const float al = __expf(ms[qj] - mn);
                ls[qj] *= al;
#pragma unroll
                for (int di = 0; di < 4; ++di) {
                    O[di][qj][0] *= al; O[di][qj][1] *= al;
                    O[di][qj][2] *= al; O[di][qj][3] *= al;
                }
                ms[qj] = mn;
            }
            float ps = 0.f;
#pragma unroll
            for (int m = 0; m < 4; ++m)
#pragma unroll
                for (int r = 0; r < 4; ++r) {
                    const float p = __expf(St[m][qj][r] - ms[qj]);
                    St[m][qj][r] = p; ps += p;
                }
            ps += __shfl_xor(ps, 16);
            ps += __shfl_xor(ps, 32);
            ls[qj] += ps;
        }

        // P fragments from St regs (k-map {4g+j, 16+4g+(j-4)})
        half8 pf[2][2];
#pragma unroll
        for (int qj = 0; qj < 2; ++qj)
#pragma unroll
            for (int kt = 0; kt < 2; ++kt) {
                half8 p;
                p[0] = (_Float16)St[2 * kt][qj][0]; p[1] = (_Float16)St[2 * kt][qj][1];
                p[2] = (_Float16)St[2 * kt][qj][2]; p[3] = (_Float16)St[2 * kt][qj][3];
                p[4] = (_Float16)St[2 * kt + 1][qj][0]; p[5] = (_Float16)St[2 * kt + 1][qj][1];
                p[6] = (_Float16)St[2 * kt + 1][qj][2]; p[7] = (_Float16)St[2 * kt + 1][qj][3];
                pf[qj][kt] = p;
            }

        // O^T[d][q] += V^T · P^T (V frags use the same split k-map)
#pragma unroll
        for (int kt = 0; kt < 2; ++kt)
#pragma unroll
            for (int di = 0; di < 4; ++di) {
                half4 lo = *(half4*)&Vl[cur][16 * di + l15][kt * 32 + 4 * g];
                half4 hi = *(half4*)&Vl[cur][16 * di + l15][kt * 32 + 16 + 4 * g];
                half8 vf;
                vf[0] = lo[0]; vf[1] = lo[1]; vf[2] = lo[2]; vf[3] = lo[3];
                vf[4] = hi[0]; vf[5] = hi[1]; vf[6] = hi[2]; vf[7] = hi[3];
#pragma unroll
                for (int qj = 0; qj < 2; ++qj)
                    O[di][qj] = MFMA16(vf, pf[qj][kt], O[di][qj]);
            }
    }

    // epilogue: normalized partial O/l -> P[kvh], L = m + log(l) -> Lb
    _Float16* P = kvh ? P1 : P0;
#pragma unroll
    for (int qj = 0; qj < 2; ++qj) {
        const float inv = 1.0f / ls[qj];
        const int q = s0 + 16 * qj + l15;
        const int r = q * 4 + b;
        _Float16* dst = P + (size_t)r * 512 + h * 64;
#pragma unroll
        for (int di = 0; di < 4; ++di) {
            half4 o;
            o[0] = (_Float16)(O[di][qj][0] * inv); o[1] = (_Float16)(O[di][qj][1] * inv);
            o[2] = (_Float16)(O[di][qj][2] * inv); o[3] = (_Float16)(O[di][qj][3] * inv);
            *(half4*)(dst + 16 * di + 4 * g) = o;
        }
        if (g == 0)
            Lb[(size_t)kvh * 65536 + r * 8 + h] = ms[qj] + __logf(ls[qj]);
    }
}

// ---------------- K2b: merge the two kv-half partials ----------------
__global__ __launch_bounds__(256) void merge_attn(
    const _Float16* __restrict__ P0, const _Float16* __restrict__ P1,
    const float* __restrict__ Lb, _Float16* __restrict__ AO)
{
    const size_t e = ((size_t)blockIdx.x * 256 + threadIdx.x) * 8;
    const int r = (int)(e >> 9);
    const int h = (int)((e & 511) >> 6);
    const int li = r * 8 + h;
    const float L0 = Lb[li], L1 = Lb[65536 + li];
    const float mm = fmaxf(L0, L1);
    const float w0 = __expf(L0 - mm), w1 = __expf(L1 - mm);
    const float inv = 1.0f / (w0 + w1);
    const float a0 = w0 * inv, a1 = w1 * inv;
    half8 x0 = *(const half8*)(P0 + e);
    half8 x1 = *(const half8*)(P1 + e);
    half8 o;
#pragma unroll
    for (int i = 0; i < 8; ++i)
        o[i] = (_Float16)(a0 * (float)x0[i] + a1 * (float)x1[i]);
    *(half8*)(AO + e) = o;
}

// ---------------- K3: output projection (f16 inputs, f32 out) ----------------
__global__ __launch_bounds__(256) void oproj_mfma(
    const _Float16* __restrict__ A, const _Float16* __restrict__ W,
    const float* __restrict__ bias, float* __restrict__ Out)
{
    __shared__ _Float16 As[128][72];
    __shared__ _Float16 Bs[64][72];
    const int tid = threadIdx.x;
    const int lane = tid & 63, wv = tid >> 6;
    const int l15 = lane & 15, g = lane >> 4;
    const int wr = wv >> 1, wc = wv & 1;
    const int j0 = blockIdx.x * 64, r0 = blockIdx.y * 128;
    f32x4 acc[4][2] = {};
    const int arow = tid >> 1, ahf = tid & 1;
    const int brow = tid >> 2, bc = tid & 3;
    for (int k0 = 0; k0 < 512; k0 += 64) {
        const _Float16* srca = A + (size_t)(r0 + arow) * 512 + k0 + ahf * 32;
#pragma unroll
        for (int c = 0; c < 4; ++c)
            *(half8*)&As[arow][ahf * 32 + c * 8] = *(const half8*)(srca + c * 8);
        const _Float16* srcb = W + (size_t)(j0 + brow) * 512 + k0 + bc * 16;
#pragma unroll
        for (int c = 0; c < 2; ++c)
            *(half8*)&Bs[brow][bc * 16 + c * 8] = *(const half8*)(srcb + c * 8);
        __syncthreads();
#pragma unroll
        for (int kt = 0; kt < 2; ++kt) {
            half8 bf0 = *(half8*)&Bs[32 * wc + l15][kt * 32 + g * 8];
            half8 bf1 = *(half8*)&Bs[32 * wc + 16 + l15][kt * 32 + g * 8];
#pragma unroll
            for (int ri = 0; ri < 4; ++ri) {
                half8 af = *(half8*)&As[64 * wr + 16 * ri + l15][kt * 32 + g * 8];
                acc[ri][0] = MFMA16(af, bf0, acc[ri][0]);
                acc[ri][1] = MFMA16(af, bf1, acc[ri][1]);
            }
        }
        __syncthreads();
    }
#pragma unroll
    for (int ri = 0; ri < 4; ++ri) {
#pragma unroll
        for (int cj = 0; cj < 2; ++cj) {
            const int col = j0 + 32 * wc + 16 * cj + l15;
            const float bv = bias[col];
#pragma unroll
            for (int r = 0; r < 4; ++r) {
                const int row = r0 + 64 * wr + 16 * ri + 4 * g + r;
                Out[(size_t)row * 512 + col] = acc[ri][cj][r] + bv;
            }
        }
    }
}

extern "C" void kernel_launch(void* const* d_in, const int* in_sizes, int n_in,
                              void* d_out, int out_size, void* d_ws, size_t ws_size,
                              hipStream_t stream)
{
    (void)in_sizes; (void)n_in; (void)out_size; (void)ws_size;
    const float* X    = (const float*)d_in[0];  // (S,B,D)
    const float* Mask = (const float*)d_in[1];  // (H,S,S)
    const float* gate = (const float*)d_in[2];  // (1,B,1)
    const float* Wi   = (const float*)d_in[3];  // (3D,D)
    const float* bi   = (const float*)d_in[4];  // (3D)
    const float* Wo   = (const float*)d_in[5];  // (D,D)
    const float* bo   = (const float*)d_in[6];  // (D)
    _Float16* ws = (_Float16*)d_ws;
    const size_t plane = (size_t)4 * 8 * 2048 * 64;  // 4,194,304 f16 elems
    _Float16* Qh  = ws;
    _Float16* Kh  = ws + plane;
    _Float16* Vt  = ws + 2 * plane;
    _Float16* AO  = ws + 3 * plane;
    _Float16* Xh  = ws + 4 * plane;              // dead after qkv; aliased by P0
    _Float16* Wih = ws + 5 * plane;              // 786,432
    _Float16* Woh = ws + 5 * plane + 786432;     // 262,144 (live until oproj)
    _Float16* P0  = Xh;                          // partial half 0 (aliases Xh)
    _Float16* P1  = ws + 5 * plane + 1048576;    // partial half 1
    float*    Lb  = (float*)(ws + 5 * plane + 1048576 + plane);  // 131072 f32

    cvt_f16<<<dim3(2560), 256, 0, stream>>>(X, Wi, Wo, Xh, Wih, Woh);
    qkv_mfma<<<dim3(24, 64), 256, 0, stream>>>(Xh, Wih, bi, gate, Qh, Kh, Vt);
    attn_mfma<<<dim3(1024), 256, 0, stream>>>(Qh, Kh, Vt, Mask, P0, P1, Lb);
    merge_attn<<<dim3(2048), 256, 0, stream>>>(P0, P1, Lb, AO);
    oproj_mfma<<<dim3(8, 64), 256, 0, stream>>>(AO, Woh, bo, (float*)d_out);
}

// Round 7
// 139.947 us; speedup vs baseline: 1.6187x; 1.0376x over previous
//
#include <hip/hip_runtime.h>
#include <cstdint>
#include <cstddef>

typedef _Float16 half8 __attribute__((ext_vector_type(8)));
typedef _Float16 half4 __attribute__((ext_vector_type(4)));
typedef float f32x4 __attribute__((ext_vector_type(4)));

#define MFMA16(A,B,C) __builtin_amdgcn_mfma_f32_16x16x32_f16(A,B,C,0,0,0)

// global -> LDS direct copy, 16B per lane: lds dest = uniform base + lane*16
__device__ __forceinline__ void gll16(const _Float16* g, _Float16* l) {
    __builtin_amdgcn_global_load_lds(
        (const __attribute__((address_space(1))) void*)g,
        (__attribute__((address_space(3))) void*)l, 16, 0, 0);
}

// ---------------- K0: bulk f32 -> f16 convert (X, Wi, Wo) ----------------
__global__ __launch_bounds__(256) void cvt_f16(
    const float* __restrict__ X, const float* __restrict__ Wi, const float* __restrict__ Wo,
    _Float16* __restrict__ Xh, _Float16* __restrict__ Wih, _Float16* __restrict__ Woh)
{
    const size_t i8 = ((size_t)blockIdx.x * 256 + threadIdx.x) * 8;
    const size_t NX = (size_t)4194304, NWI = 786432;
    const float* src; _Float16* dst; size_t off;
    if (i8 < NX) { src = X; dst = Xh; off = i8; }
    else if (i8 < NX + NWI) { src = Wi; dst = Wih; off = i8 - NX; }
    else { src = Wo; dst = Woh; off = i8 - NX - NWI; }
    f32x4 v0 = *(const f32x4*)(src + off);
    f32x4 v1 = *(const f32x4*)(src + off + 4);
    half8 r;
    r[0]=(_Float16)v0[0]; r[1]=(_Float16)v0[1]; r[2]=(_Float16)v0[2]; r[3]=(_Float16)v0[3];
    r[4]=(_Float16)v1[0]; r[5]=(_Float16)v1[1]; r[6]=(_Float16)v1[2]; r[7]=(_Float16)v1[3];
    *(half8*)(dst + off) = r;
}

// ---------------- K1: QKV projection (f16 MFMA, f16 inputs) ----------------
// V^T is written PRE-PERMUTED within each 32-col group: s -> (s&~31)|8g|4hi|j
// (g=(s>>2)&3, hi=(s>>4)&1, j=s&3) so attention's PV fragments are contiguous.
__global__ __launch_bounds__(256) void qkv_mfma(
    const _Float16* __restrict__ X, const _Float16* __restrict__ W,
    const float* __restrict__ bias, const float* __restrict__ gate,
    _Float16* __restrict__ Qo, _Float16* __restrict__ Ko, _Float16* __restrict__ Vt)
{
    __shared__ _Float16 As[128][72];
    __shared__ _Float16 Bs[64][72];
    const int tid = threadIdx.x;
    const int lane = tid & 63, wv = tid >> 6;
    const int l15 = lane & 15, g = lane >> 4;
    const int wr = wv >> 1, wc = wv & 1;
    const int j0 = blockIdx.x * 64, r0 = blockIdx.y * 128;
    f32x4 acc[4][2] = {};
    const int arow = tid >> 1, ahf = tid & 1;
    const int brow = tid >> 2, bc = tid & 3;
    for (int k0 = 0; k0 < 512; k0 += 64) {
        const _Float16* srca = X + (size_t)(r0 + arow) * 512 + k0 + ahf * 32;
#pragma unroll
        for (int c = 0; c < 4; ++c)
            *(half8*)&As[arow][ahf * 32 + c * 8] = *(const half8*)(srca + c * 8);
        const _Float16* srcb = W + (size_t)(j0 + brow) * 512 + k0 + bc * 16;
#pragma unroll
        for (int c = 0; c < 2; ++c)
            *(half8*)&Bs[brow][bc * 16 + c * 8] = *(const half8*)(srcb + c * 8);
        __syncthreads();
#pragma unroll
        for (int kt = 0; kt < 2; ++kt) {
            half8 bf0 = *(half8*)&Bs[32 * wc + l15][kt * 32 + g * 8];
            half8 bf1 = *(half8*)&Bs[32 * wc + 16 + l15][kt * 32 + g * 8];
#pragma unroll
            for (int ri = 0; ri < 4; ++ri) {
                half8 af = *(half8*)&As[64 * wr + 16 * ri + l15][kt * 32 + g * 8];
                acc[ri][0] = MFMA16(af, bf0, acc[ri][0]);
                acc[ri][1] = MFMA16(af, bf1, acc[ri][1]);
            }
        }
        __syncthreads();
    }
#pragma unroll
    for (int ri = 0; ri < 4; ++ri) {
#pragma unroll
        for (int cj = 0; cj < 2; ++cj) {
            const int col = j0 + 32 * wc + 16 * cj + l15;
            const int sec = col >> 9, hh = (col >> 6) & 7, d = col & 63;
            const float bv = bias[col];
#pragma unroll
            for (int r = 0; r < 4; ++r) {
                const int row = r0 + 64 * wr + 16 * ri + 4 * g + r;
                const int b = row & 3, s = row >> 2;
                const float v = acc[ri][cj][r];
                if (sec == 0)
                    Qo[((size_t)(b * 8 + hh) * 2048 + s) * 64 + d] = (_Float16)((v + bv) * 0.125f);
                else if (sec == 1)
                    Ko[((size_t)(b * 8 + hh) * 2048 + s) * 64 + d] = (_Float16)(v + bv);
                else {
                    const int ps = (s & ~31) | ((s & 12) << 1) | ((s & 16) >> 2) | (s & 3);
                    Vt[((size_t)(b * 8 + hh) * 64 + d) * 2048 + ps] = (_Float16)(v * gate[b] + bv);
                }
            }
        }
    }
}

// ---------------- K2: flash attention, 64 q-rows/wave, gll staging, static softmax ----
// Block = 2 waves, 128 q-rows, one kv-half (1024 kv). Wave 0 stages K, wave 1 stages V
// via global_load_lds with XOR-swizzled source blocks. LDS [64][64] linear:
// LDS[r][blk] = G[r][blk ^ (r&7)].  Static softmax: P = exp(S), per-lane l partials.
__global__ __launch_bounds__(128, 2) void attn_mfma(
    const _Float16* __restrict__ Q, const _Float16* __restrict__ K,
    const _Float16* __restrict__ V, const float* __restrict__ M,
    _Float16* __restrict__ P0, _Float16* __restrict__ P1, float* __restrict__ Lb)
{
    __shared__ _Float16 Kl[2][4096];
    __shared__ _Float16 Vl[2][4096];
    const int tid = threadIdx.x;
    const int lane = tid & 63, w = tid >> 6;
    const int l15 = lane & 15, g = lane >> 4;
    const int bsw = l15 & 7;
    const int bid = blockIdx.x;
    const int h = bid & 7, b = (bid >> 3) & 3, sg = (bid >> 5) & 15, kvh = bid >> 9;
    const int s0 = sg * 128 + w * 64;
    const size_t bh = (size_t)b * 8 + h;
    const _Float16* Qp = Q + bh * 2048 * 64;
    const _Float16* Kp = K + bh * 2048 * 64 + (size_t)kvh * 1024 * 64;
    const _Float16* Vp = V + bh * 64 * 2048 + kvh * 1024;   // permuted [d][s]
    const float* Mp = M + (size_t)h * 2048 * 2048 + kvh * 1024;

    // Q fragments (64 rows, pre-scaled by 1/8 in qkv)
    half8 qf[4][2];
#pragma unroll
    for (int qj = 0; qj < 4; ++qj)
#pragma unroll
        for (int dh = 0; dh < 2; ++dh)
            qf[qj][dh] = *(const half8*)(Qp + (size_t)(s0 + 16 * qj + l15) * 64 + dh * 32 + g * 8);

    // gll staging lane params
    const int grow = lane >> 3, gcb = lane & 7;

    // prologue: stage tile 0 into buf 0
    if (w == 0) {
#pragma unroll
        for (int c = 0; c < 8; ++c) {
            const int r = c * 8 + grow;
            gll16(Kp + (size_t)r * 64 + ((gcb ^ (r & 7)) * 8), &Kl[0][c * 512]);
        }
    } else {
#pragma unroll
        for (int c = 0; c < 8; ++c) {
            const int d = c * 8 + grow;
            gll16(Vp + (size_t)d * 2048 + ((gcb ^ (d & 7)) * 8), &Vl[0][c * 512]);
        }
    }
    // mask for tile 0 phase A (m = 0,1)
    f32x4 mc0[2][4], mc1[2][4];
#pragma unroll
    for (int mi = 0; mi < 2; ++mi)
#pragma unroll
        for (int qj = 0; qj < 4; ++qj)
            mc0[mi][qj] = *(const f32x4*)(Mp + (size_t)(s0 + 16 * qj + l15) * 2048 + 16 * mi + 4 * g);

    f32x4 O[4][4] = {};
    float l[4] = {0.f, 0.f, 0.f, 0.f};
    __syncthreads();

    for (int tl = 0; tl < 16; ++tl) {
        const int cur = tl & 1;
        const int t0 = tl * 64;
        const int tn = ((tl + 1) & 15) * 64;
        // stage next tile into buf^1 (lands before this tile's end barrier)
        if (tl < 15) {
            if (w == 0) {
#pragma unroll
                for (int c = 0; c < 8; ++c) {
                    const int r = c * 8 + grow;
                    gll16(Kp + (size_t)(t0 + 64 + r) * 64 + ((gcb ^ (r & 7)) * 8),
                          &Kl[cur ^ 1][c * 512]);
                }
            } else {
#pragma unroll
                for (int c = 0; c < 8; ++c) {
                    const int d = c * 8 + grow;
                    gll16(Vp + (size_t)d * 2048 + t0 + 64 + ((gcb ^ (d & 7)) * 8),
                          &Vl[cur ^ 1][c * 512]);
                }
            }
        }

        // ---------------- phase A: m = 0,1 ; kv-half kh = 0 ----------------
        f32x4 St[2][4];
        __builtin_amdgcn_s_setprio(1);
#pragma unroll
        for (int mi = 0; mi < 2; ++mi) {
            const int row = 16 * mi + l15;
            half8 kf0 = *(half8*)&Kl[cur][row * 64 + ((g) ^ bsw) * 8];
            half8 kf1 = *(half8*)&Kl[cur][row * 64 + ((4 + g) ^ bsw) * 8];
#pragma unroll
            for (int qj = 0; qj < 4; ++qj) {
                St[mi][qj] = MFMA16(kf0, qf[qj][0], mc0[mi][qj]);
                St[mi][qj] = MFMA16(kf1, qf[qj][1], St[mi][qj]);
            }
        }
        __builtin_amdgcn_s_setprio(0);
        // issue phase-B mask loads (m = 2,3 at t0)
#pragma unroll
        for (int mi = 0; mi < 2; ++mi)
#pragma unroll
            for (int qj = 0; qj < 4; ++qj)
                mc1[mi][qj] = *(const f32x4*)(Mp + (size_t)(s0 + 16 * qj + l15) * 2048 + t0 + 16 * (2 + mi) + 4 * g);
        // static softmax partial + P fragments
        half8 pfA[4];
#pragma unroll
        for (int qj = 0; qj < 4; ++qj) {
            float e00 = __expf(St[0][qj][0]), e01 = __expf(St[0][qj][1]);
            float e02 = __expf(St[0][qj][2]), e03 = __expf(St[0][qj][3]);
            float e10 = __expf(St[1][qj][0]), e11 = __expf(St[1][qj][1]);
            float e12 = __expf(St[1][qj][2]), e13 = __expf(St[1][qj][3]);
            l[qj] += ((e00 + e01) + (e02 + e03)) + ((e10 + e11) + (e12 + e13));
            half8 p;
            p[0] = (_Float16)e00; p[1] = (_Float16)e01; p[2] = (_Float16)e02; p[3] = (_Float16)e03;
            p[4] = (_Float16)e10; p[5] = (_Float16)e11; p[6] = (_Float16)e12; p[7] = (_Float16)e13;
            pfA[qj] = p;
        }
        __builtin_amdgcn_s_setprio(1);
#pragma unroll
        for (int di = 0; di < 4; ++di) {
            const int vrow = 16 * di + l15;
            half8 vf = *(half8*)&Vl[cur][vrow * 64 + ((g) ^ bsw) * 8];
#pragma unroll
            for (int qj = 0; qj < 4; ++qj)
                O[di][qj] = MFMA16(vf, pfA[qj], O[di][qj]);
        }
        __builtin_amdgcn_s_setprio(0);

        // ---------------- phase B: m = 2,3 ; kv-half kh = 1 ----------------
        __builtin_amdgcn_s_setprio(1);
#pragma unroll
        for (int mi = 0; mi < 2; ++mi) {
            const int row = 16 * (2 + mi) + l15;
            half8 kf0 = *(half8*)&Kl[cur][row * 64 + ((g) ^ bsw) * 8];
            half8 kf1 = *(half8*)&Kl[cur][row * 64 + ((4 + g) ^ bsw) * 8];
#pragma unroll
            for (int qj = 0; qj < 4; ++qj) {
                St[mi][qj] = MFMA16(kf0, qf[qj][0], mc1[mi][qj]);
                St[mi][qj] = MFMA16(kf1, qf[qj][1], St[mi][qj]);
            }
        }
        __builtin_amdgcn_s_setprio(0);
        // issue next tile's phase-A mask loads (m = 0,1 at tn)
#pragma unroll
        for (int mi = 0; mi < 2; ++mi)
#pragma unroll
            for (int qj = 0; qj < 4; ++qj)
                mc0[mi][qj] = *(const f32x4*)(Mp + (size_t)(s0 + 16 * qj + l15) * 2048 + tn + 16 * mi + 4 * g);
        half8 pfB[4];
#pragma unroll
        for (int qj = 0; qj < 4; ++qj) {
            float e00 = __expf(St[0][qj][0]), e01 = __expf(St[0][qj][1]);
            float e02 = __expf(St[0][qj][2]), e03 = __expf(St[0][qj][3]);
            float e10 = __expf(St[1][qj][0]), e11 = __expf(St[1][qj][1]);
            float e12 = __expf(St[1][qj][2]), e13 = __expf(St[1][qj][3]);
            l[qj] += ((e00 + e01) + (e02 + e03)) + ((e10 + e11) + (e12 + e13));
            half8 p;
            p[0] = (_Float16)e00; p[1] = (_Float16)e01; p[2] = (_Float16)e02; p[3] = (_Float16)e03;
            p[4] = (_Float16)e10; p[5] = (_Float16)e11; p[6] = (_Float16)e12; p[7] = (_Float16)e13;
            pfB[qj] = p;
        }
        __builtin_amdgcn_s_setprio(1);
#pragma unroll
        for (int di = 0; di < 4; ++di) {
            const int vrow = 16 * di + l15;
            half8 vf = *(half8*)&Vl[cur][vrow * 64 + ((4 + g) ^ bsw) * 8];
#pragma unroll
            for (int qj = 0; qj < 4; ++qj)
                O[di][qj] = MFMA16(vf, pfB[qj], O[di][qj]);
        }
        __builtin_amdgcn_s_setprio(0);

        __syncthreads();   // drains gll (vmcnt) + LDS; next tile's buffer ready
    }

    // epilogue: reduce l across g-groups, write normalized partial + l
    _Float16* P = kvh ? P1 : P0;
#pragma unroll
    for (int qj = 0; qj < 4; ++qj) {
        float lt = l[qj];
        lt += __shfl_xor(lt, 16);
        lt += __shfl_xor(lt, 32);
        const float inv = 1.0f / lt;
        const int q = s0 + 16 * qj + l15;
        const int r = q * 4 + b;
        _Float16* dst = P + (size_t)r * 512 + h * 64;
#pragma unroll
        for (int di = 0; di < 4; ++di) {
            half4 o;
            o[0] = (_Float16)(O[di][qj][0] * inv); o[1] = (_Float16)(O[di][qj][1] * inv);
            o[2] = (_Float16)(O[di][qj][2] * inv); o[3] = (_Float16)(O[di][qj][3] * inv);
            *(half4*)(dst + 16 * di + 4 * g) = o;
        }
        if (g == 0)
            Lb[(size_t)kvh * 65536 + r * 8 + h] = lt;
    }
}

// ---------------- K2b: merge the two kv-half partials (raw-l weights) ----------------
__global__ __launch_bounds__(256) void merge_attn(
    const _Float16* __restrict__ P0, const _Float16* __restrict__ P1,
    const float* __restrict__ Lb, _Float16* __restrict__ AO)
{
    const size_t e = ((size_t)blockIdx.x * 256 + threadIdx.x) * 8;
    const int r = (int)(e >> 9);
    const int h = (int)((e & 511) >> 6);
    const int li = r * 8 + h;
    const float l0 = Lb[li], l1 = Lb[65536 + li];
    const float inv = 1.0f / (l0 + l1);
    const float a0 = l0 * inv, a1 = l1 * inv;
    half8 x0 = *(const half8*)(P0 + e);
    half8 x1 = *(const half8*)(P1 + e);
    half8 o;
#pragma unroll
    for (int i = 0; i < 8; ++i)
        o[i] = (_Float16)(a0 * (float)x0[i] + a1 * (float)x1[i]);
    *(half8*)(AO + e) = o;
}

// ---------------- K3: output projection (f16 inputs, f32 out) ----------------
__global__ __launch_bounds__(256) void oproj_mfma(
    const _Float16* __restrict__ A, const _Float16* __restrict__ W,
    const float* __restrict__ bias, float* __restrict__ Out)
{
    __shared__ _Float16 As[128][72];
    __shared__ _Float16 Bs[64][72];
    const int tid = threadIdx.x;
    const int lane = tid & 63, wv = tid >> 6;
    const int l15 = lane & 15, g = lane >> 4;
    const int wr = wv >> 1, wc = wv & 1;
    const int j0 = blockIdx.x * 64, r0 = blockIdx.y * 128;
    f32x4 acc[4][2] = {};
    const int arow = tid >> 1, ahf = tid & 1;
    const int brow = tid >> 2, bc = tid & 3;
    for (int k0 = 0; k0 < 512; k0 += 64) {
        const _Float16* srca = A + (size_t)(r0 + arow) * 512 + k0 + ahf * 32;
#pragma unroll
        for (int c = 0; c < 4; ++c)
            *(half8*)&As[arow][ahf * 32 + c * 8] = *(const half8*)(srca + c * 8);
        const _Float16* srcb = W + (size_t)(j0 + brow) * 512 + k0 + bc * 16;
#pragma unroll
        for (int c = 0; c < 2; ++c)
            *(half8*)&Bs[brow][bc * 16 + c * 8] = *(const half8*)(srcb + c * 8);
        __syncthreads();
#pragma unroll
        for (int kt = 0; kt < 2; ++kt) {
            half8 bf0 = *(half8*)&Bs[32 * wc + l15][kt * 32 + g * 8];
            half8 bf1 = *(half8*)&Bs[32 * wc + 16 + l15][kt * 32 + g * 8];
#pragma unroll
            for (int ri = 0; ri < 4; ++ri) {
                half8 af = *(half8*)&As[64 * wr + 16 * ri + l15][kt * 32 + g * 8];
                acc[ri][0] = MFMA16(af, bf0, acc[ri][0]);
                acc[ri][1] = MFMA16(af, bf1, acc[ri][1]);
            }
        }
        __syncthreads();
    }
#pragma unroll
    for (int ri = 0; ri < 4; ++ri) {
#pragma unroll
        for (int cj = 0; cj < 2; ++cj) {
            const int col = j0 + 32 * wc + 16 * cj + l15;
            const float bv = bias[col];
#pragma unroll
            for (int r = 0; r < 4; ++r) {
                const int row = r0 + 64 * wr + 16 * ri + 4 * g + r;
                Out[(size_t)row * 512 + col] = acc[ri][cj][r] + bv;
            }
        }
    }
}

extern "C" void kernel_launch(void* const* d_in, const int* in_sizes, int n_in,
                              void* d_out, int out_size, void* d_ws, size_t ws_size,
                              hipStream_t stream)
{
    (void)in_sizes; (void)n_in; (void)out_size; (void)ws_size;
    const float* X    = (const float*)d_in[0];  // (S,B,D)
    const float* Mask = (const float*)d_in[1];  // (H,S,S)
    const float* gate = (const float*)d_in[2];  // (1,B,1)
    const float* Wi   = (const float*)d_in[3];  // (3D,D)
    const float* bi   = (const float*)d_in[4];  // (3D)
    const float* Wo   = (const float*)d_in[5];  // (D,D)
    const float* bo   = (const float*)d_in[6];  // (D)
    _Float16* ws = (_Float16*)d_ws;
    const size_t plane = (size_t)4 * 8 * 2048 * 64;  // 4,194,304 f16 elems
    _Float16* Qh  = ws;
    _Float16* Kh  = ws + plane;
    _Float16* Vt  = ws + 2 * plane;              // pre-permuted V^T
    _Float16* AO  = ws + 3 * plane;
    _Float16* Xh  = ws + 4 * plane;              // dead after qkv; aliased by P0
    _Float16* Wih = ws + 5 * plane;              // 786,432
    _Float16* Woh = ws + 5 * plane + 786432;     // 262,144 (live until oproj)
    _Float16* P0  = Xh;                          // partial half 0 (aliases Xh)
    _Float16* P1  = ws + 5 * plane + 1048576;    // partial half 1
    float*    Lb  = (float*)(ws + 5 * plane + 1048576 + plane);  // 2*65536 f32

    cvt_f16<<<dim3(2560), 256, 0, stream>>>(X, Wi, Wo, Xh, Wih, Woh);
    qkv_mfma<<<dim3(24, 64), 256, 0, stream>>>(Xh, Wih, bi, gate, Qh, Kh, Vt);
    attn_mfma<<<dim3(1024), 128, 0, stream>>>(Qh, Kh, Vt, Mask, P0, P1, Lb);
    merge_attn<<<dim3(2048), 256, 0, stream>>>(P0, P1, Lb, AO);
    oproj_mfma<<<dim3(8, 64), 256, 0, stream>>>(AO, Woh, bo, (float*)d_out);
}